// Round 6
// baseline (300.109 us; speedup 1.0000x reference)
//
#include <hip/hip_runtime.h>
#include <hip/hip_fp16.h>
#include <math.h>

#define NN 40000
#define EE 640000
#define EP 680000   // EE + NN (self loops)
#define FIN0 32
#define HC 128      // H*C
#define GG 1000
#define MM 256
#define NR 8        // histogram replicas (R14: de-contend CSR atomics)
#define SCAN_BLOCKS ((NN + 255) / 256)   // 157
#define PROJ0_BLOCKS (NN / 64)           // 625
#define HIST_BLOCKS ((EP + 255) / 256)   // 2657
#define PADH 136    // LDS half-pitch: >=128, multiple of 8 (16B align), 17x16B row stride

typedef _Float16 f16x8 __attribute__((ext_vector_type(8)));
typedef float f32x4 __attribute__((ext_vector_type(4)));

// ---------------- merged prep: proj0 (vector, FIN=32) || hist || W->Wt fp16 ----------------
// R9: hist's contended atomics and proj0 are independent; one launch overlaps them.
// R14: hist replicated 8-way. R13 PMC: prep 44us, VALU 7%, Occ 17%, 0.9 TB/s ->
// latency-bound on same-line atomic RMW chains (~270 edges/64B line of deg).
// deg8[r*NN+d] with r=idx&7 spreads each line's chain 8x (~34 serialized ops).

__global__ __launch_bounds__(256) void prep_kernel(const float* __restrict__ X,
                                                   const float* __restrict__ W0,
                                                   const float* __restrict__ a_src,
                                                   const float* __restrict__ a_dst,
                                                   __half* __restrict__ H2,
                                                   float* __restrict__ als,
                                                   float* __restrict__ ald,
                                                   const int* __restrict__ ei,
                                                   int* __restrict__ deg8,
                                                   int* __restrict__ rank,
                                                   const float* __restrict__ W1,
                                                   const float* __restrict__ W2,
                                                   __half* __restrict__ Wt1,
                                                   __half* __restrict__ Wt2) {
    int t = threadIdx.x;
    int b = blockIdx.x;
    if (b >= PROJ0_BLOCKS && b < PROJ0_BLOCKS + HIST_BLOCKS) {
        int idx = (b - PROJ0_BLOCKS) * 256 + t;
        if (idx < EP) {
            int d = (idx < EE) ? ei[EE + idx] : (idx - EE);
            int r = idx & (NR - 1);
            rank[idx] = atomicAdd(&deg8[r * NN + d], 1);
        }
        return;
    }
    if (b >= PROJ0_BLOCKS + HIST_BLOCKS) {
        // 2 blocks: transpose+cast W1/W2 (128x128) into Wt[c][k] fp16.
        int l = b - (PROJ0_BLOCKS + HIST_BLOCKS);
        const float* Wsrc = (l == 0) ? W1 : W2;
        __half* Wd = (l == 0) ? Wt1 : Wt2;
#pragma unroll 8
        for (int r = 0; r < 64; r++) {
            int idx = r * 256 + t;
            int k = idx >> 7, c = idx & 127;
            Wd[c * 128 + k] = __float2half(Wsrc[idx]);
        }
        return;
    }
    // ---- proj0: 64 nodes x 128 chans, 4x8 micro-tile, K=32 single tile ----
    __shared__ float xs[32][68];
    __shared__ float ws[32][128];
    int node0 = b * 64;
    int nt = t & 15;
    int ct = t >> 4;
    float acc[4][8];
#pragma unroll
    for (int i = 0; i < 4; i++)
#pragma unroll
        for (int j = 0; j < 8; j++) acc[i][j] = 0.f;
#pragma unroll
    for (int r = 0; r < 8; r++) {
        int idx = r * 256 + t;
        int n = idx >> 5, k = idx & 31;
        xs[k][n] = X[(node0 + n) * FIN0 + k];
    }
#pragma unroll
    for (int r = 0; r < 16; r++) {
        int idx = r * 256 + t;
        int k = idx >> 7, c = idx & 127;
        ws[k][c] = W0[k * 128 + c];
    }
    __syncthreads();
#pragma unroll
    for (int k = 0; k < 32; k++) {
        const float4 xv = *(const float4*)(&xs[k][4 * nt]);
        const float4 wa = *(const float4*)(&ws[k][8 * ct]);
        const float4 wb = *(const float4*)(&ws[k][8 * ct + 4]);
        float xr[4] = {xv.x, xv.y, xv.z, xv.w};
        float wr[8] = {wa.x, wa.y, wa.z, wa.w, wb.x, wb.y, wb.z, wb.w};
#pragma unroll
        for (int i = 0; i < 4; i++)
#pragma unroll
            for (int j = 0; j < 8; j++) acc[i][j] = fmaf(xr[i], wr[j], acc[i][j]);
    }
#pragma unroll
    for (int i = 0; i < 4; i++) {
        int n = node0 + 4 * nt + i;
        __half2 p0 = __floats2half2_rn(acc[i][0], acc[i][1]);
        __half2 p1 = __floats2half2_rn(acc[i][2], acc[i][3]);
        __half2 p2 = __floats2half2_rn(acc[i][4], acc[i][5]);
        __half2 p3 = __floats2half2_rn(acc[i][6], acc[i][7]);
        uint4 pk;
        pk.x = *(unsigned*)&p0; pk.y = *(unsigned*)&p1;
        pk.z = *(unsigned*)&p2; pk.w = *(unsigned*)&p3;
        *(uint4*)(&H2[(size_t)n * HC + 8 * ct]) = pk;
    }
    float sa[4] = {0.f, 0.f, 0.f, 0.f}, da[4] = {0.f, 0.f, 0.f, 0.f};
#pragma unroll
    for (int j = 0; j < 8; j++) {
        float av = a_src[ct * 8 + j];
        float dv = a_dst[ct * 8 + j];
#pragma unroll
        for (int i = 0; i < 4; i++) {
            sa[i] = fmaf(acc[i][j], av, sa[i]);
            da[i] = fmaf(acc[i][j], dv, da[i]);
        }
    }
#pragma unroll
    for (int i = 0; i < 4; i++) {
        sa[i] += __shfl_xor(sa[i], 16);
        da[i] += __shfl_xor(da[i], 16);
    }
    if ((ct & 1) == 0) {
        int head = ct >> 1;
#pragma unroll
        for (int i = 0; i < 4; i++) {
            int n = node0 + 4 * nt + i;
            als[n * 8 + head] = sa[i];
            ald[n * 8 + head] = da[i];
        }
    }
}

// ---------------- CSR scan/scatter (R14: sums 8 replicas; emits roff) ----------------

__global__ __launch_bounds__(256) void scan_partial(const int* __restrict__ deg8,
                                                    int* __restrict__ part) {
    int b = blockIdx.x, t = threadIdx.x;
    int i = b * 256 + t;
    int v = 0;
    if (i < NN) {
#pragma unroll
        for (int r = 0; r < NR; r++) v += deg8[r * NN + i];
    }
#pragma unroll
    for (int d = 1; d < 64; d <<= 1) v += __shfl_xor(v, d);
    __shared__ int ws[4];
    if ((t & 63) == 0) ws[t >> 6] = v;
    __syncthreads();
    if (t == 0) part[b] = ws[0] + ws[1] + ws[2] + ws[3];
}

__global__ __launch_bounds__(256) void scan_final(const int* __restrict__ deg8,
                                                  const int* __restrict__ part,
                                                  int* __restrict__ offs,
                                                  int* __restrict__ roff) {
    int b = blockIdx.x, t = threadIdx.x;
    __shared__ int sbase;
    if (t < 64) {
        int s = 0;
        for (int l = t; l < b; l += 64) s += part[l];
#pragma unroll
        for (int d = 1; d < 64; d <<= 1) s += __shfl_xor(s, d);
        if (t == 0) sbase = s;
    }
    int i = b * 256 + t;
    int dv[NR];
    int v = 0;
    if (i < NN) {
#pragma unroll
        for (int r = 0; r < NR; r++) { dv[r] = deg8[r * NN + i]; v += dv[r]; }
    }
    __shared__ int tmp[256];
    tmp[t] = v;
    __syncthreads();
    for (int st = 1; st < 256; st <<= 1) {
        int add = (t >= st) ? tmp[t - st] : 0;
        __syncthreads();
        tmp[t] += add;
        __syncthreads();
    }
    int excl = tmp[t] - v + sbase;
    if (i < NN) {
        offs[i] = excl;
        int acc = excl;
#pragma unroll
        for (int r = 0; r < NR; r++) { roff[r * NN + i] = acc; acc += dv[r]; }
    }
    if (i == NN - 1) offs[NN] = excl + v;
}

__global__ void scatter_kernel(const int* __restrict__ ei, const int* __restrict__ roff,
                               const int* __restrict__ rank, int* __restrict__ esrc) {
    int idx = blockIdx.x * 256 + threadIdx.x;
    if (idx >= EP) return;
    int s, d;
    if (idx < EE) { s = ei[idx]; d = ei[EE + idx]; } else { s = idx - EE; d = s; }
    int r = idx & (NR - 1);
    esrc[roff[r * NN + d] + rank[idx]] = s;
}

// ---------------- MFMA projection for layers 1-2 (FIN = HC = 128) ----------------
// R9-R11: mfma_f32_16x16x32_f16, 32 MFMA/wave, K=128 in 4 k-steps; staging walks
// fixed in R10 (Ws) and R11 (As + H2 writeback). Verified R11 @ absmax 1.2e-4.
// Layouts (m89-verified family): A row=l&15,k=(l>>4)*8+i; B k=(l>>4)*8+i,col=l&15;
// C/D col=l&15,row=(l>>4)*4+j.
// LDS: As 64xPADH + Ws 128xPADH halves = 52.2 KB -> 3 blocks/CU; grid 625.

__global__ __launch_bounds__(256) void proj_mfma(const __half* __restrict__ Bin,
                                                 const __half* __restrict__ Wt,
                                                 const float* __restrict__ a_src,
                                                 const float* __restrict__ a_dst,
                                                 __half* __restrict__ H2,
                                                 float* __restrict__ als,
                                                 float* __restrict__ ald) {
    __shared__ __half As[64 * PADH];
    __shared__ __half Ws[128 * PADH];
    int t = threadIdx.x;
    int node0 = blockIdx.x * 64;
    {   // stage A-tile: 64 nodes x 128 k fp16 = 1024 uint4, 4 per thread
        int n = t >> 2, kk = (t & 3) * 32;
        const uint4* src = (const uint4*)(&Bin[(size_t)(node0 + n) * 128 + kk]);
        uint4 v0 = src[0];
        uint4 v1 = src[1];
        uint4 v2 = src[2];
        uint4 v3 = src[3];
        uint4* dst = (uint4*)(&As[n * PADH + kk]);   // PADH*2B = 272 = 17x16B
        dst[0] = v0; dst[1] = v1; dst[2] = v2; dst[3] = v3;
    }
#pragma unroll
    for (int r = 0; r < 8; r++) {  // stage Wt: 128 rows x 16 chunks of 8 halves
        int idx = r * 256 + t;
        int c = idx >> 4;
        int kk = (idx & 15) * 8;
        uint4 v = *(const uint4*)(&Wt[c * 128 + kk]);
        *(uint4*)(&Ws[c * PADH + kk]) = v;
    }
    __syncthreads();
    int w = t >> 6, l = t & 63;
    int lr = l & 15, lg = l >> 4;
    f32x4 acc[8];
    f32x4 z4 = {0.f, 0.f, 0.f, 0.f};
#pragma unroll
    for (int n = 0; n < 8; n++) acc[n] = z4;
    const __half* arow = &As[(16 * w + lr) * PADH + lg * 8];
#pragma unroll
    for (int ks = 0; ks < 4; ks++) {
        f16x8 af = *(const f16x8*)(arow + 32 * ks);
#pragma unroll
        for (int n = 0; n < 8; n++) {
            f16x8 bf = *(const f16x8*)(&Ws[(16 * n + lr) * PADH + lg * 8 + 32 * ks]);
            acc[n] = __builtin_amdgcn_mfma_f32_16x16x32_f16(af, bf, acc[n], 0, 0, 0);
        }
    }
    // write C tile (fp16) into own 16 rows of As; wave-private rows, DS in-order
    // per wave and the writes depend on the MFMA results.
#pragma unroll
    for (int n = 0; n < 8; n++)
#pragma unroll
        for (int j = 0; j < 4; j++)
            As[(16 * w + lg * 4 + j) * PADH + 16 * n + lr] = __float2half(acc[n][j]);
    __syncthreads();
    {   // coalesced H2 write-back: 4 uint4 per thread, contiguous
        int n = t >> 2, kk = (t & 3) * 32;
        const uint4* src = (const uint4*)(&As[n * PADH + kk]);
        uint4 v0 = src[0];
        uint4 v1 = src[1];
        uint4 v2 = src[2];
        uint4 v3 = src[3];
        uint4* dst = (uint4*)(&H2[(size_t)(node0 + n) * 128 + kk]);
        dst[0] = v0; dst[1] = v1; dst[2] = v2; dst[3] = v3;
    }
    {   // attention logits from the fp16 tile (same mapping as proj0 epilogue)
        int nt = t & 15, ct = t >> 4;
        float av[8], dv[8];
#pragma unroll
        for (int j = 0; j < 8; j++) { av[j] = a_src[ct * 8 + j]; dv[j] = a_dst[ct * 8 + j]; }
        float sa[4], da[4];
#pragma unroll
        for (int i = 0; i < 4; i++) {
            uint4 hv = *(const uint4*)(&As[(4 * nt + i) * PADH + 8 * ct]);
            __half2 h0 = *(__half2*)&hv.x;
            __half2 h1 = *(__half2*)&hv.y;
            __half2 h2 = *(__half2*)&hv.z;
            __half2 h3 = *(__half2*)&hv.w;
            float2 f0 = __half22float2(h0);
            float2 f1 = __half22float2(h1);
            float2 f2 = __half22float2(h2);
            float2 f3 = __half22float2(h3);
            sa[i] = f0.x * av[0] + f0.y * av[1] + f1.x * av[2] + f1.y * av[3] +
                    f2.x * av[4] + f2.y * av[5] + f3.x * av[6] + f3.y * av[7];
            da[i] = f0.x * dv[0] + f0.y * dv[1] + f1.x * dv[2] + f1.y * dv[3] +
                    f2.x * dv[4] + f2.y * dv[5] + f3.x * dv[6] + f3.y * dv[7];
        }
#pragma unroll
        for (int i = 0; i < 4; i++) {
            sa[i] += __shfl_xor(sa[i], 16);
            da[i] += __shfl_xor(da[i], 16);
        }
        if ((ct & 1) == 0) {
            int head = ct >> 1;
#pragma unroll
            for (int i = 0; i < 4; i++) {
                int n = node0 + 4 * nt + i;
                als[n * 8 + head] = sa[i];
                ald[n * 8 + head] = da[i];
            }
        }
    }
}

// ---------------- fused softmax + aggregation per dst node ----------------
// R11 form (verified). At the random-256B-gather ceiling (~3.6 TB/s; confirmed by
// two failed locality splits, R8 and R12). HALF_OUT: layers 0/1 emit fp16 B2,
// layer 2 fp32 B for the MLP.

template <bool HALF_OUT>
__global__ __launch_bounds__(256) void agg_kernel(const __half* __restrict__ H2,
                                                  const float* __restrict__ als,
                                                  const float* __restrict__ ald,
                                                  const int* __restrict__ offs,
                                                  const int* __restrict__ esrc,
                                                  const float* __restrict__ bias,
                                                  float* __restrict__ OUT,
                                                  __half* __restrict__ OUT2) {
    int t = threadIdx.x;
    int n = blockIdx.x * 4 + (t >> 6);
    int t6 = t & 63;
    int c8 = t6 & 15;          // channel group: chans [8*c8, 8*c8+8)
    int slot = (t6 >> 4) & 3;  // 4 edge slots per wave
    int hd = c8 >> 1;
    int beg = offs[n], end = offs[n + 1];
    float ad = ald[n * 8 + hd];
    float acc[8] = {0.f, 0.f, 0.f, 0.f, 0.f, 0.f, 0.f, 0.f};
    float denom = 0.f;
    const float4* H4 = (const float4*)H2;   // 8 halves per float4

    int p = beg + slot;
    int s_cur = 0; float al_cur = 0.f;
    if (p < end) {
        s_cur = esrc[p];
        al_cur = als[s_cur * 8 + hd];
    }
#pragma unroll 2
    while (p < end) {
        int pn = p + 4;
        int s_nxt = 0;
        if (pn < end) s_nxt = esrc[pn];
        float x = al_cur + ad;
        x = (x > 0.f) ? x : 0.2f * x;
        float w = __expf(x);
        float4 r = H4[(size_t)s_cur * 16 + c8];
        float al_nxt = 0.f;
        if (pn < end) al_nxt = als[s_nxt * 8 + hd];
        __half2 h0 = *(__half2*)&r.x;
        __half2 h1 = *(__half2*)&r.y;
        __half2 h2 = *(__half2*)&r.z;
        __half2 h3 = *(__half2*)&r.w;
        float2 f0 = __half22float2(h0);
        float2 f1 = __half22float2(h1);
        float2 f2 = __half22float2(h2);
        float2 f3 = __half22float2(h3);
        acc[0] = fmaf(w, f0.x, acc[0]); acc[1] = fmaf(w, f0.y, acc[1]);
        acc[2] = fmaf(w, f1.x, acc[2]); acc[3] = fmaf(w, f1.y, acc[3]);
        acc[4] = fmaf(w, f2.x, acc[4]); acc[5] = fmaf(w, f2.y, acc[5]);
        acc[6] = fmaf(w, f3.x, acc[6]); acc[7] = fmaf(w, f3.y, acc[7]);
        denom += w;
        s_cur = s_nxt; al_cur = al_nxt;
        p = pn;
    }
#pragma unroll
    for (int j = 0; j < 8; j++) {
        acc[j] += __shfl_xor(acc[j], 16);
        acc[j] += __shfl_xor(acc[j], 32);
    }
    denom += __shfl_xor(denom, 16);
    denom += __shfl_xor(denom, 32);
    if (slot == 0 && t6 < 16) {
        float inv = 1.0f / denom;
        const float4 ba = ((const float4*)bias)[2 * c8];
        const float4 bb = ((const float4*)bias)[2 * c8 + 1];
        float o0 = fmaxf(fmaf(acc[0], inv, ba.x), 0.f);
        float o1 = fmaxf(fmaf(acc[1], inv, ba.y), 0.f);
        float o2 = fmaxf(fmaf(acc[2], inv, ba.z), 0.f);
        float o3 = fmaxf(fmaf(acc[3], inv, ba.w), 0.f);
        float o4 = fmaxf(fmaf(acc[4], inv, bb.x), 0.f);
        float o5 = fmaxf(fmaf(acc[5], inv, bb.y), 0.f);
        float o6 = fmaxf(fmaf(acc[6], inv, bb.z), 0.f);
        float o7 = fmaxf(fmaf(acc[7], inv, bb.w), 0.f);
        if (HALF_OUT) {
            __half2 q0 = __floats2half2_rn(o0, o1);
            __half2 q1 = __floats2half2_rn(o2, o3);
            __half2 q2 = __floats2half2_rn(o4, o5);
            __half2 q3 = __floats2half2_rn(o6, o7);
            uint4 pk;
            pk.x = *(unsigned*)&q0; pk.y = *(unsigned*)&q1;
            pk.z = *(unsigned*)&q2; pk.w = *(unsigned*)&q3;
            ((uint4*)OUT2)[(size_t)n * 16 + c8] = pk;
        } else {
            float4 v0, v1;
            v0.x = o0; v0.y = o1; v0.z = o2; v0.w = o3;
            v1.x = o4; v1.y = o5; v1.z = o6; v1.w = o7;
            ((float4*)OUT)[(size_t)n * 32 + 2 * c8]     = v0;
            ((float4*)OUT)[(size_t)n * 32 + 2 * c8 + 1] = v1;
        }
    }
}

// ---------------- fused mean-pool + MLP + head (2 graphs/block, 500 blocks) ----------------

__global__ __launch_bounds__(256) void mlp_fused(const float* __restrict__ B,
                                                 const int* __restrict__ batch,
                                                 const float* __restrict__ fW0,
                                                 const float* __restrict__ fb0,
                                                 const float* __restrict__ fW1,
                                                 const float* __restrict__ fb1,
                                                 const float* __restrict__ oW,
                                                 const float* __restrict__ ob,
                                                 float* __restrict__ out) {
    __shared__ int lo[3];
    __shared__ float rows[2][128];
    __shared__ float g1s[2][256];
    __shared__ float g2s[2][256];
    int t = threadIdx.x;
    int g0 = blockIdx.x * 2;
    if (t < 3) {
        int target = g0 + t;
        int a = 0, b = NN;
        while (a < b) { int mid = (a + b) >> 1; if (batch[mid] < target) a = mid + 1; else b = mid; }
        lo[t] = a;
    }
    __syncthreads();
    {
        int j = t >> 7, c = t & 127;
        int s0 = lo[j], s1 = lo[j + 1];
        float s = 0.f;
        float p0 = 0.f, p1 = 0.f, p2 = 0.f, p3 = 0.f;
        int n = s0;
        for (; n + 3 < s1; n += 4) {
            p0 += B[(size_t)n * 128 + c];
            p1 += B[(size_t)(n + 1) * 128 + c];
            p2 += B[(size_t)(n + 2) * 128 + c];
            p3 += B[(size_t)(n + 3) * 128 + c];
        }
        for (; n < s1; n++) s += B[(size_t)n * 128 + c];
        s += (p0 + p1) + (p2 + p3);
        rows[j][c] = s / fmaxf((float)(s1 - s0), 1.0f);
    }
    __syncthreads();
    float a0 = 0.f, a1 = 0.f;
#pragma unroll 8
    for (int k = 0; k < 128; k++) {
        float w = fW0[k * 256 + t];
        a0 = fmaf(rows[0][k], w, a0);
        a1 = fmaf(rows[1][k], w, a1);
    }
    float b0v = fb0[t];
    g1s[0][t] = fmaxf(a0 + b0v, 0.f);
    g1s[1][t] = fmaxf(a1 + b0v, 0.f);
    __syncthreads();
    a0 = 0.f; a1 = 0.f;
#pragma unroll 8
    for (int k = 0; k < 256; k++) {
        float w = fW1[k * 256 + t];
        a0 = fmaf(g1s[0][k], w, a0);
        a1 = fmaf(g1s[1][k], w, a1);
    }
    float b1v = fb1[t];
    g2s[0][t] = fmaxf(a0 + b1v, 0.f);
    g2s[1][t] = fmaxf(a1 + b1v, 0.f);
    __syncthreads();
    if (t < 64) {
        int jj = t >> 5, l = t & 31;
        float p0 = 0.f, p1 = 0.f;
#pragma unroll
        for (int k = l; k < 256; k += 32) {
            float v = g2s[jj][k];
            p0 = fmaf(v, oW[k * 2 + 0], p0);
            p1 = fmaf(v, oW[k * 2 + 1], p1);
        }
#pragma unroll
        for (int d = 1; d < 32; d <<= 1) {
            p0 += __shfl_xor(p0, d);
            p1 += __shfl_xor(p1, d);
        }
        if (l == 0) {
            out[(g0 + jj) * 2 + 0] = p0 + ob[0];
            out[(g0 + jj) * 2 + 1] = p1 + ob[1];
        }
    }
}

// ---------------- launch ----------------

extern "C" void kernel_launch(void* const* d_in, const int* in_sizes, int n_in,
                              void* d_out, int out_size, void* d_ws, size_t ws_size,
                              hipStream_t stream) {
    const float* x    = (const float*)d_in[0];
    const int* ei     = (const int*)d_in[1];
    const int* batch  = (const int*)d_in[2];
    const float* W[3]   = {(const float*)d_in[3], (const float*)d_in[7],  (const float*)d_in[11]};
    const float* bs[3]  = {(const float*)d_in[4], (const float*)d_in[8],  (const float*)d_in[12]};
    const float* asr[3] = {(const float*)d_in[5], (const float*)d_in[9],  (const float*)d_in[13]};
    const float* adt[3] = {(const float*)d_in[6], (const float*)d_in[10], (const float*)d_in[14]};
    const float* fW0 = (const float*)d_in[15];
    const float* fb0 = (const float*)d_in[16];
    const float* fW1 = (const float*)d_in[17];
    const float* fb1 = (const float*)d_in[18];
    const float* oW  = (const float*)d_in[19];
    const float* ob  = (const float*)d_in[20];
    float* out = (float*)d_out;

    char* base = (char*)d_ws;
    size_t off = 0;
    auto alloc = [&](size_t bytes) -> void* {
        void* p = base + off;
        off += (bytes + 255) & ~(size_t)255;
        return p;
    };
    int* deg8   = (int*)alloc((size_t)NR * NN * 4);
    int* offs   = (int*)alloc((size_t)(NN + 1) * 4);
    int* roff   = (int*)alloc((size_t)NR * NN * 4);
    int* part   = (int*)alloc((size_t)SCAN_BLOCKS * 4);
    int* rank   = (int*)alloc((size_t)EP * 4);
    int* esrc   = (int*)alloc((size_t)EP * 4);
    __half* H2  = (__half*)alloc((size_t)NN * HC * 2);
    float* B    = (float*)alloc((size_t)NN * HC * 4);
    __half* B2  = (__half*)alloc((size_t)NN * HC * 2);
    float* als  = (float*)alloc((size_t)NN * 8 * 4);
    float* ald  = (float*)alloc((size_t)NN * 8 * 4);
    __half* Wt1 = (__half*)alloc((size_t)HC * HC * 2);
    __half* Wt2 = (__half*)alloc((size_t)HC * HC * 2);

    hipMemsetAsync(deg8, 0, (size_t)NR * NN * 4, stream);

    prep_kernel<<<PROJ0_BLOCKS + HIST_BLOCKS + 2, 256, 0, stream>>>(
        x, W[0], asr[0], adt[0], H2, als, ald, ei, deg8, rank, W[1], W[2], Wt1, Wt2);
    scan_partial<<<SCAN_BLOCKS, 256, 0, stream>>>(deg8, part);
    scan_final<<<SCAN_BLOCKS, 256, 0, stream>>>(deg8, part, offs, roff);
    scatter_kernel<<<(EP + 255) / 256, 256, 0, stream>>>(ei, roff, rank, esrc);

    agg_kernel<true><<<NN / 4, 256, 0, stream>>>(H2, als, ald, offs, esrc, bs[0], nullptr, B2);
    proj_mfma<<<PROJ0_BLOCKS, 256, 0, stream>>>(B2, Wt1, asr[1], adt[1], H2, als, ald);
    agg_kernel<true><<<NN / 4, 256, 0, stream>>>(H2, als, ald, offs, esrc, bs[1], nullptr, B2);
    proj_mfma<<<PROJ0_BLOCKS, 256, 0, stream>>>(B2, Wt2, asr[2], adt[2], H2, als, ald);
    agg_kernel<false><<<NN / 4, 256, 0, stream>>>(H2, als, ald, offs, esrc, bs[2], B, nullptr);

    mlp_fused<<<GG / 2, 256, 0, stream>>>(B, batch, fW0, fb0, fW1, fb1, oW, ob, out);
}

// Round 7
// 294.991 us; speedup vs baseline: 1.0173x; 1.0173x over previous
//
#include <hip/hip_runtime.h>
#include <hip/hip_fp16.h>
#include <math.h>

#define NN 40000
#define EE 640000
#define EP 680000   // EE + NN (self loops)
#define FIN0 32
#define HC 128      // H*C
#define GG 1000
#define MM 256
#define SCAN_BLOCKS ((NN + 255) / 256)   // 157
#define PROJ0_BLOCKS (NN / 64)           // 625
#define HIST_ILP 8
#define HIST8_BLOCKS ((EP + 2047) / 2048)  // 333 (256 thr x 8 edges)
#define PADH 136    // LDS half-pitch: >=128, multiple of 8 (16B align), 17x16B row stride

typedef _Float16 f16x8 __attribute__((ext_vector_type(8)));
typedef float f32x4 __attribute__((ext_vector_type(4)));

// ---------------- merged prep: proj0 (vector, FIN=32) || hist || W->Wt fp16 ----------------
// R9: merge overlaps independent phases. R14 post-mortem: hist is NOT
// contention-bound (8-way replication = null); it is MLP-starved — one returning
// device atomic (~900cyc) in flight per thread, and prep's 84VGPR/25KB-LDS caps
// residency at ~24 waves/CU -> ~6.8 atomic-ops/cyc -> 42us. R15: 8 edges/thread,
// 8 independent atomics issued back-to-back per thread -> ~8x MLP.

__global__ __launch_bounds__(256) void prep_kernel(const float* __restrict__ X,
                                                   const float* __restrict__ W0,
                                                   const float* __restrict__ a_src,
                                                   const float* __restrict__ a_dst,
                                                   __half* __restrict__ H2,
                                                   float* __restrict__ als,
                                                   float* __restrict__ ald,
                                                   const int* __restrict__ ei,
                                                   int* __restrict__ deg,
                                                   int* __restrict__ rank,
                                                   const float* __restrict__ W1,
                                                   const float* __restrict__ W2,
                                                   __half* __restrict__ Wt1,
                                                   __half* __restrict__ Wt2) {
    int t = threadIdx.x;
    int b = blockIdx.x;
    if (b >= PROJ0_BLOCKS && b < PROJ0_BLOCKS + HIST8_BLOCKS) {
        int base = (b - PROJ0_BLOCKS) * (256 * HIST_ILP) + t;
        int dd[HIST_ILP], rr[HIST_ILP];
#pragma unroll
        for (int k = 0; k < HIST_ILP; k++) {
            int idx = base + k * 256;
            dd[k] = (idx < EP) ? ((idx < EE) ? ei[EE + idx] : (idx - EE)) : -1;
        }
#pragma unroll
        for (int k = 0; k < HIST_ILP; k++) {
            if (dd[k] >= 0) rr[k] = atomicAdd(&deg[dd[k]], 1);
        }
#pragma unroll
        for (int k = 0; k < HIST_ILP; k++) {
            int idx = base + k * 256;
            if (idx < EP) rank[idx] = rr[k];
        }
        return;
    }
    if (b >= PROJ0_BLOCKS + HIST8_BLOCKS) {
        // 2 blocks: transpose+cast W1/W2 (128x128) into Wt[c][k] fp16.
        int l = b - (PROJ0_BLOCKS + HIST8_BLOCKS);
        const float* Wsrc = (l == 0) ? W1 : W2;
        __half* Wd = (l == 0) ? Wt1 : Wt2;
#pragma unroll 8
        for (int r = 0; r < 64; r++) {
            int idx = r * 256 + t;
            int k = idx >> 7, c = idx & 127;
            Wd[c * 128 + k] = __float2half(Wsrc[idx]);
        }
        return;
    }
    // ---- proj0: 64 nodes x 128 chans, 4x8 micro-tile, K=32 single tile ----
    __shared__ float xs[32][68];
    __shared__ float ws[32][128];
    int node0 = b * 64;
    int nt = t & 15;
    int ct = t >> 4;
    float acc[4][8];
#pragma unroll
    for (int i = 0; i < 4; i++)
#pragma unroll
        for (int j = 0; j < 8; j++) acc[i][j] = 0.f;
#pragma unroll
    for (int r = 0; r < 8; r++) {
        int idx = r * 256 + t;
        int n = idx >> 5, k = idx & 31;
        xs[k][n] = X[(node0 + n) * FIN0 + k];
    }
#pragma unroll
    for (int r = 0; r < 16; r++) {
        int idx = r * 256 + t;
        int k = idx >> 7, c = idx & 127;
        ws[k][c] = W0[k * 128 + c];
    }
    __syncthreads();
#pragma unroll
    for (int k = 0; k < 32; k++) {
        const float4 xv = *(const float4*)(&xs[k][4 * nt]);
        const float4 wa = *(const float4*)(&ws[k][8 * ct]);
        const float4 wb = *(const float4*)(&ws[k][8 * ct + 4]);
        float xr[4] = {xv.x, xv.y, xv.z, xv.w};
        float wr[8] = {wa.x, wa.y, wa.z, wa.w, wb.x, wb.y, wb.z, wb.w};
#pragma unroll
        for (int i = 0; i < 4; i++)
#pragma unroll
            for (int j = 0; j < 8; j++) acc[i][j] = fmaf(xr[i], wr[j], acc[i][j]);
    }
#pragma unroll
    for (int i = 0; i < 4; i++) {
        int n = node0 + 4 * nt + i;
        __half2 p0 = __floats2half2_rn(acc[i][0], acc[i][1]);
        __half2 p1 = __floats2half2_rn(acc[i][2], acc[i][3]);
        __half2 p2 = __floats2half2_rn(acc[i][4], acc[i][5]);
        __half2 p3 = __floats2half2_rn(acc[i][6], acc[i][7]);
        uint4 pk;
        pk.x = *(unsigned*)&p0; pk.y = *(unsigned*)&p1;
        pk.z = *(unsigned*)&p2; pk.w = *(unsigned*)&p3;
        *(uint4*)(&H2[(size_t)n * HC + 8 * ct]) = pk;
    }
    float sa[4] = {0.f, 0.f, 0.f, 0.f}, da[4] = {0.f, 0.f, 0.f, 0.f};
#pragma unroll
    for (int j = 0; j < 8; j++) {
        float av = a_src[ct * 8 + j];
        float dv = a_dst[ct * 8 + j];
#pragma unroll
        for (int i = 0; i < 4; i++) {
            sa[i] = fmaf(acc[i][j], av, sa[i]);
            da[i] = fmaf(acc[i][j], dv, da[i]);
        }
    }
#pragma unroll
    for (int i = 0; i < 4; i++) {
        sa[i] += __shfl_xor(sa[i], 16);
        da[i] += __shfl_xor(da[i], 16);
    }
    if ((ct & 1) == 0) {
        int head = ct >> 1;
#pragma unroll
        for (int i = 0; i < 4; i++) {
            int n = node0 + 4 * nt + i;
            als[n * 8 + head] = sa[i];
            ald[n * 8 + head] = da[i];
        }
    }
}

// ---------------- CSR scan/scatter (R13 form, single deg) ----------------

__global__ __launch_bounds__(256) void scan_partial(const int* __restrict__ deg,
                                                    int* __restrict__ part) {
    int b = blockIdx.x, t = threadIdx.x;
    int i = b * 256 + t;
    int v = (i < NN) ? deg[i] : 0;
#pragma unroll
    for (int d = 1; d < 64; d <<= 1) v += __shfl_xor(v, d);
    __shared__ int ws[4];
    if ((t & 63) == 0) ws[t >> 6] = v;
    __syncthreads();
    if (t == 0) part[b] = ws[0] + ws[1] + ws[2] + ws[3];
}

__global__ __launch_bounds__(256) void scan_final(const int* __restrict__ deg,
                                                  const int* __restrict__ part,
                                                  int* __restrict__ offs) {
    int b = blockIdx.x, t = threadIdx.x;
    __shared__ int sbase;
    if (t < 64) {
        int s = 0;
        for (int l = t; l < b; l += 64) s += part[l];
#pragma unroll
        for (int d = 1; d < 64; d <<= 1) s += __shfl_xor(s, d);
        if (t == 0) sbase = s;
    }
    int i = b * 256 + t;
    int v = (i < NN) ? deg[i] : 0;
    __shared__ int tmp[256];
    tmp[t] = v;
    __syncthreads();
    for (int st = 1; st < 256; st <<= 1) {
        int add = (t >= st) ? tmp[t - st] : 0;
        __syncthreads();
        tmp[t] += add;
        __syncthreads();
    }
    int excl = tmp[t] - v + sbase;
    if (i < NN) offs[i] = excl;
    if (i == NN - 1) offs[NN] = excl + v;
}

__global__ void scatter_kernel(const int* __restrict__ ei, const int* __restrict__ offs,
                               const int* __restrict__ rank, int* __restrict__ esrc) {
    int idx = blockIdx.x * 256 + threadIdx.x;
    if (idx >= EP) return;
    int s, d;
    if (idx < EE) { s = ei[idx]; d = ei[EE + idx]; } else { s = idx - EE; d = s; }
    esrc[offs[d] + rank[idx]] = s;
}

// ---------------- MFMA projection for layers 1-2 (FIN = HC = 128) ----------------
// R9-R11: mfma_f32_16x16x32_f16, 32 MFMA/wave, K=128 in 4 k-steps; staging walks
// fixed in R10 (Ws) and R11 (As + H2 writeback). Verified R11 @ absmax 1.2e-4.
// Layouts (m89-verified family): A row=l&15,k=(l>>4)*8+i; B k=(l>>4)*8+i,col=l&15;
// C/D col=l&15,row=(l>>4)*4+j.
// LDS: As 64xPADH + Ws 128xPADH halves = 52.2 KB -> 3 blocks/CU; grid 625.

__global__ __launch_bounds__(256) void proj_mfma(const __half* __restrict__ Bin,
                                                 const __half* __restrict__ Wt,
                                                 const float* __restrict__ a_src,
                                                 const float* __restrict__ a_dst,
                                                 __half* __restrict__ H2,
                                                 float* __restrict__ als,
                                                 float* __restrict__ ald) {
    __shared__ __half As[64 * PADH];
    __shared__ __half Ws[128 * PADH];
    int t = threadIdx.x;
    int node0 = blockIdx.x * 64;
    {   // stage A-tile: 64 nodes x 128 k fp16 = 1024 uint4, 4 per thread
        int n = t >> 2, kk = (t & 3) * 32;
        const uint4* src = (const uint4*)(&Bin[(size_t)(node0 + n) * 128 + kk]);
        uint4 v0 = src[0];
        uint4 v1 = src[1];
        uint4 v2 = src[2];
        uint4 v3 = src[3];
        uint4* dst = (uint4*)(&As[n * PADH + kk]);   // PADH*2B = 272 = 17x16B
        dst[0] = v0; dst[1] = v1; dst[2] = v2; dst[3] = v3;
    }
#pragma unroll
    for (int r = 0; r < 8; r++) {  // stage Wt: 128 rows x 16 chunks of 8 halves
        int idx = r * 256 + t;
        int c = idx >> 4;
        int kk = (idx & 15) * 8;
        uint4 v = *(const uint4*)(&Wt[c * 128 + kk]);
        *(uint4*)(&Ws[c * PADH + kk]) = v;
    }
    __syncthreads();
    int w = t >> 6, l = t & 63;
    int lr = l & 15, lg = l >> 4;
    f32x4 acc[8];
    f32x4 z4 = {0.f, 0.f, 0.f, 0.f};
#pragma unroll
    for (int n = 0; n < 8; n++) acc[n] = z4;
    const __half* arow = &As[(16 * w + lr) * PADH + lg * 8];
#pragma unroll
    for (int ks = 0; ks < 4; ks++) {
        f16x8 af = *(const f16x8*)(arow + 32 * ks);
#pragma unroll
        for (int n = 0; n < 8; n++) {
            f16x8 bf = *(const f16x8*)(&Ws[(16 * n + lr) * PADH + lg * 8 + 32 * ks]);
            acc[n] = __builtin_amdgcn_mfma_f32_16x16x32_f16(af, bf, acc[n], 0, 0, 0);
        }
    }
    // write C tile (fp16) into own 16 rows of As; wave-private rows, DS in-order
    // per wave and the writes depend on the MFMA results.
#pragma unroll
    for (int n = 0; n < 8; n++)
#pragma unroll
        for (int j = 0; j < 4; j++)
            As[(16 * w + lg * 4 + j) * PADH + 16 * n + lr] = __float2half(acc[n][j]);
    __syncthreads();
    {   // coalesced H2 write-back: 4 uint4 per thread, contiguous
        int n = t >> 2, kk = (t & 3) * 32;
        const uint4* src = (const uint4*)(&As[n * PADH + kk]);
        uint4 v0 = src[0];
        uint4 v1 = src[1];
        uint4 v2 = src[2];
        uint4 v3 = src[3];
        uint4* dst = (uint4*)(&H2[(size_t)(node0 + n) * 128 + kk]);
        dst[0] = v0; dst[1] = v1; dst[2] = v2; dst[3] = v3;
    }
    {   // attention logits from the fp16 tile (same mapping as proj0 epilogue)
        int nt = t & 15, ct = t >> 4;
        float av[8], dv[8];
#pragma unroll
        for (int j = 0; j < 8; j++) { av[j] = a_src[ct * 8 + j]; dv[j] = a_dst[ct * 8 + j]; }
        float sa[4], da[4];
#pragma unroll
        for (int i = 0; i < 4; i++) {
            uint4 hv = *(const uint4*)(&As[(4 * nt + i) * PADH + 8 * ct]);
            __half2 h0 = *(__half2*)&hv.x;
            __half2 h1 = *(__half2*)&hv.y;
            __half2 h2 = *(__half2*)&hv.z;
            __half2 h3 = *(__half2*)&hv.w;
            float2 f0 = __half22float2(h0);
            float2 f1 = __half22float2(h1);
            float2 f2 = __half22float2(h2);
            float2 f3 = __half22float2(h3);
            sa[i] = f0.x * av[0] + f0.y * av[1] + f1.x * av[2] + f1.y * av[3] +
                    f2.x * av[4] + f2.y * av[5] + f3.x * av[6] + f3.y * av[7];
            da[i] = f0.x * dv[0] + f0.y * dv[1] + f1.x * dv[2] + f1.y * dv[3] +
                    f2.x * dv[4] + f2.y * dv[5] + f3.x * dv[6] + f3.y * dv[7];
        }
#pragma unroll
        for (int i = 0; i < 4; i++) {
            sa[i] += __shfl_xor(sa[i], 16);
            da[i] += __shfl_xor(da[i], 16);
        }
        if ((ct & 1) == 0) {
            int head = ct >> 1;
#pragma unroll
            for (int i = 0; i < 4; i++) {
                int n = node0 + 4 * nt + i;
                als[n * 8 + head] = sa[i];
                ald[n * 8 + head] = da[i];
            }
        }
    }
}

// ---------------- fused softmax + aggregation per dst node ----------------
// R11 form (verified). At the random-256B-gather ceiling (~3.6 TB/s; confirmed by
// two failed locality splits, R8 and R12). HALF_OUT: layers 0/1 emit fp16 B2,
// layer 2 fp32 B for the MLP.

template <bool HALF_OUT>
__global__ __launch_bounds__(256) void agg_kernel(const __half* __restrict__ H2,
                                                  const float* __restrict__ als,
                                                  const float* __restrict__ ald,
                                                  const int* __restrict__ offs,
                                                  const int* __restrict__ esrc,
                                                  const float* __restrict__ bias,
                                                  float* __restrict__ OUT,
                                                  __half* __restrict__ OUT2) {
    int t = threadIdx.x;
    int n = blockIdx.x * 4 + (t >> 6);
    int t6 = t & 63;
    int c8 = t6 & 15;          // channel group: chans [8*c8, 8*c8+8)
    int slot = (t6 >> 4) & 3;  // 4 edge slots per wave
    int hd = c8 >> 1;
    int beg = offs[n], end = offs[n + 1];
    float ad = ald[n * 8 + hd];
    float acc[8] = {0.f, 0.f, 0.f, 0.f, 0.f, 0.f, 0.f, 0.f};
    float denom = 0.f;
    const float4* H4 = (const float4*)H2;   // 8 halves per float4

    int p = beg + slot;
    int s_cur = 0; float al_cur = 0.f;
    if (p < end) {
        s_cur = esrc[p];
        al_cur = als[s_cur * 8 + hd];
    }
#pragma unroll 2
    while (p < end) {
        int pn = p + 4;
        int s_nxt = 0;
        if (pn < end) s_nxt = esrc[pn];
        float x = al_cur + ad;
        x = (x > 0.f) ? x : 0.2f * x;
        float w = __expf(x);
        float4 r = H4[(size_t)s_cur * 16 + c8];
        float al_nxt = 0.f;
        if (pn < end) al_nxt = als[s_nxt * 8 + hd];
        __half2 h0 = *(__half2*)&r.x;
        __half2 h1 = *(__half2*)&r.y;
        __half2 h2 = *(__half2*)&r.z;
        __half2 h3 = *(__half2*)&r.w;
        float2 f0 = __half22float2(h0);
        float2 f1 = __half22float2(h1);
        float2 f2 = __half22float2(h2);
        float2 f3 = __half22float2(h3);
        acc[0] = fmaf(w, f0.x, acc[0]); acc[1] = fmaf(w, f0.y, acc[1]);
        acc[2] = fmaf(w, f1.x, acc[2]); acc[3] = fmaf(w, f1.y, acc[3]);
        acc[4] = fmaf(w, f2.x, acc[4]); acc[5] = fmaf(w, f2.y, acc[5]);
        acc[6] = fmaf(w, f3.x, acc[6]); acc[7] = fmaf(w, f3.y, acc[7]);
        denom += w;
        s_cur = s_nxt; al_cur = al_nxt;
        p = pn;
    }
#pragma unroll
    for (int j = 0; j < 8; j++) {
        acc[j] += __shfl_xor(acc[j], 16);
        acc[j] += __shfl_xor(acc[j], 32);
    }
    denom += __shfl_xor(denom, 16);
    denom += __shfl_xor(denom, 32);
    if (slot == 0 && t6 < 16) {
        float inv = 1.0f / denom;
        const float4 ba = ((const float4*)bias)[2 * c8];
        const float4 bb = ((const float4*)bias)[2 * c8 + 1];
        float o0 = fmaxf(fmaf(acc[0], inv, ba.x), 0.f);
        float o1 = fmaxf(fmaf(acc[1], inv, ba.y), 0.f);
        float o2 = fmaxf(fmaf(acc[2], inv, ba.z), 0.f);
        float o3 = fmaxf(fmaf(acc[3], inv, ba.w), 0.f);
        float o4 = fmaxf(fmaf(acc[4], inv, bb.x), 0.f);
        float o5 = fmaxf(fmaf(acc[5], inv, bb.y), 0.f);
        float o6 = fmaxf(fmaf(acc[6], inv, bb.z), 0.f);
        float o7 = fmaxf(fmaf(acc[7], inv, bb.w), 0.f);
        if (HALF_OUT) {
            __half2 q0 = __floats2half2_rn(o0, o1);
            __half2 q1 = __floats2half2_rn(o2, o3);
            __half2 q2 = __floats2half2_rn(o4, o5);
            __half2 q3 = __floats2half2_rn(o6, o7);
            uint4 pk;
            pk.x = *(unsigned*)&q0; pk.y = *(unsigned*)&q1;
            pk.z = *(unsigned*)&q2; pk.w = *(unsigned*)&q3;
            ((uint4*)OUT2)[(size_t)n * 16 + c8] = pk;
        } else {
            float4 v0, v1;
            v0.x = o0; v0.y = o1; v0.z = o2; v0.w = o3;
            v1.x = o4; v1.y = o5; v1.z = o6; v1.w = o7;
            ((float4*)OUT)[(size_t)n * 32 + 2 * c8]     = v0;
            ((float4*)OUT)[(size_t)n * 32 + 2 * c8 + 1] = v1;
        }
    }
}

// ---------------- fused mean-pool + MLP + head (2 graphs/block, 500 blocks) ----------------

__global__ __launch_bounds__(256) void mlp_fused(const float* __restrict__ B,
                                                 const int* __restrict__ batch,
                                                 const float* __restrict__ fW0,
                                                 const float* __restrict__ fb0,
                                                 const float* __restrict__ fW1,
                                                 const float* __restrict__ fb1,
                                                 const float* __restrict__ oW,
                                                 const float* __restrict__ ob,
                                                 float* __restrict__ out) {
    __shared__ int lo[3];
    __shared__ float rows[2][128];
    __shared__ float g1s[2][256];
    __shared__ float g2s[2][256];
    int t = threadIdx.x;
    int g0 = blockIdx.x * 2;
    if (t < 3) {
        int target = g0 + t;
        int a = 0, b = NN;
        while (a < b) { int mid = (a + b) >> 1; if (batch[mid] < target) a = mid + 1; else b = mid; }
        lo[t] = a;
    }
    __syncthreads();
    {
        int j = t >> 7, c = t & 127;
        int s0 = lo[j], s1 = lo[j + 1];
        float s = 0.f;
        float p0 = 0.f, p1 = 0.f, p2 = 0.f, p3 = 0.f;
        int n = s0;
        for (; n + 3 < s1; n += 4) {
            p0 += B[(size_t)n * 128 + c];
            p1 += B[(size_t)(n + 1) * 128 + c];
            p2 += B[(size_t)(n + 2) * 128 + c];
            p3 += B[(size_t)(n + 3) * 128 + c];
        }
        for (; n < s1; n++) s += B[(size_t)n * 128 + c];
        s += (p0 + p1) + (p2 + p3);
        rows[j][c] = s / fmaxf((float)(s1 - s0), 1.0f);
    }
    __syncthreads();
    float a0 = 0.f, a1 = 0.f;
#pragma unroll 8
    for (int k = 0; k < 128; k++) {
        float w = fW0[k * 256 + t];
        a0 = fmaf(rows[0][k], w, a0);
        a1 = fmaf(rows[1][k], w, a1);
    }
    float b0v = fb0[t];
    g1s[0][t] = fmaxf(a0 + b0v, 0.f);
    g1s[1][t] = fmaxf(a1 + b0v, 0.f);
    __syncthreads();
    a0 = 0.f; a1 = 0.f;
#pragma unroll 8
    for (int k = 0; k < 256; k++) {
        float w = fW1[k * 256 + t];
        a0 = fmaf(g1s[0][k], w, a0);
        a1 = fmaf(g1s[1][k], w, a1);
    }
    float b1v = fb1[t];
    g2s[0][t] = fmaxf(a0 + b1v, 0.f);
    g2s[1][t] = fmaxf(a1 + b1v, 0.f);
    __syncthreads();
    if (t < 64) {
        int jj = t >> 5, l = t & 31;
        float p0 = 0.f, p1 = 0.f;
#pragma unroll
        for (int k = l; k < 256; k += 32) {
            float v = g2s[jj][k];
            p0 = fmaf(v, oW[k * 2 + 0], p0);
            p1 = fmaf(v, oW[k * 2 + 1], p1);
        }
#pragma unroll
        for (int d = 1; d < 32; d <<= 1) {
            p0 += __shfl_xor(p0, d);
            p1 += __shfl_xor(p1, d);
        }
        if (l == 0) {
            out[(g0 + jj) * 2 + 0] = p0 + ob[0];
            out[(g0 + jj) * 2 + 1] = p1 + ob[1];
        }
    }
}

// ---------------- launch ----------------

extern "C" void kernel_launch(void* const* d_in, const int* in_sizes, int n_in,
                              void* d_out, int out_size, void* d_ws, size_t ws_size,
                              hipStream_t stream) {
    const float* x    = (const float*)d_in[0];
    const int* ei     = (const int*)d_in[1];
    const int* batch  = (const int*)d_in[2];
    const float* W[3]   = {(const float*)d_in[3], (const float*)d_in[7],  (const float*)d_in[11]};
    const float* bs[3]  = {(const float*)d_in[4], (const float*)d_in[8],  (const float*)d_in[12]};
    const float* asr[3] = {(const float*)d_in[5], (const float*)d_in[9],  (const float*)d_in[13]};
    const float* adt[3] = {(const float*)d_in[6], (const float*)d_in[10], (const float*)d_in[14]};
    const float* fW0 = (const float*)d_in[15];
    const float* fb0 = (const float*)d_in[16];
    const float* fW1 = (const float*)d_in[17];
    const float* fb1 = (const float*)d_in[18];
    const float* oW  = (const float*)d_in[19];
    const float* ob  = (const float*)d_in[20];
    float* out = (float*)d_out;

    char* base = (char*)d_ws;
    size_t off = 0;
    auto alloc = [&](size_t bytes) -> void* {
        void* p = base + off;
        off += (bytes + 255) & ~(size_t)255;
        return p;
    };
    int* deg    = (int*)alloc((size_t)NN * 4);
    int* offs   = (int*)alloc((size_t)(NN + 1) * 4);
    int* part   = (int*)alloc((size_t)SCAN_BLOCKS * 4);
    int* rank   = (int*)alloc((size_t)EP * 4);
    int* esrc   = (int*)alloc((size_t)EP * 4);
    __half* H2  = (__half*)alloc((size_t)NN * HC * 2);
    float* B    = (float*)alloc((size_t)NN * HC * 4);
    __half* B2  = (__half*)alloc((size_t)NN * HC * 2);
    float* als  = (float*)alloc((size_t)NN * 8 * 4);
    float* ald  = (float*)alloc((size_t)NN * 8 * 4);
    __half* Wt1 = (__half*)alloc((size_t)HC * HC * 2);
    __half* Wt2 = (__half*)alloc((size_t)HC * HC * 2);

    hipMemsetAsync(deg, 0, (size_t)NN * 4, stream);

    prep_kernel<<<PROJ0_BLOCKS + HIST8_BLOCKS + 2, 256, 0, stream>>>(
        x, W[0], asr[0], adt[0], H2, als, ald, ei, deg, rank, W[1], W[2], Wt1, Wt2);
    scan_partial<<<SCAN_BLOCKS, 256, 0, stream>>>(deg, part);
    scan_final<<<SCAN_BLOCKS, 256, 0, stream>>>(deg, part, offs);
    scatter_kernel<<<(EP + 255) / 256, 256, 0, stream>>>(ei, offs, rank, esrc);

    agg_kernel<true><<<NN / 4, 256, 0, stream>>>(H2, als, ald, offs, esrc, bs[0], nullptr, B2);
    proj_mfma<<<PROJ0_BLOCKS, 256, 0, stream>>>(B2, Wt1, asr[1], adt[1], H2, als, ald);
    agg_kernel<true><<<NN / 4, 256, 0, stream>>>(H2, als, ald, offs, esrc, bs[1], nullptr, B2);
    proj_mfma<<<PROJ0_BLOCKS, 256, 0, stream>>>(B2, Wt2, asr[2], adt[2], H2, als, ald);
    agg_kernel<false><<<NN / 4, 256, 0, stream>>>(H2, als, ald, offs, esrc, bs[2], B, nullptr);

    mlp_fused<<<GG / 2, 256, 0, stream>>>(B, batch, fW0, fb0, fW1, fb1, oW, ob, out);
}

// Round 8
// 286.882 us; speedup vs baseline: 1.0461x; 1.0283x over previous
//
#include <hip/hip_runtime.h>
#include <hip/hip_fp16.h>
#include <math.h>

#define NN 40000
#define EE 640000
#define EP 680000   // EE + NN (self loops)
#define FIN0 32
#define HC 128      // H*C
#define GG 1000
#define MM 256
#define PROJ0_BLOCKS (NN / 64)           // 625
#define NB 333      // radix blocks: 333 * 2048 >= EP
#define NBIN 157    // high-byte buckets: (NN-1)>>8 = 156
#define HSIZE (NBIN * NB)                // 52281
#define SCAN2_BLOCKS ((HSIZE + 255) / 256)  // 205
#define PADH 136    // LDS half-pitch: >=128, multiple of 8 (16B align), 17x16B row stride

typedef _Float16 f16x8 __attribute__((ext_vector_type(8)));
typedef float f32x4 __attribute__((ext_vector_type(4)));

// ---------------- merged prep: proj0 (vector, FIN=32) || H1 || W->Wt fp16 ----------------
// R16: the CSR build is rebuilt with ZERO global atomics. R13-R15 evidence:
// device atomicAdd runs at the memory-side coherence point (prep WRITE_SIZE 35MB
// = 680K x 64B RMW); contention-spread (R14) and ILP (R15) both null -> HW
// throughput wall. H1 = per-block LDS histogram of dst>>8 (157 buckets), written
// to hist[bin][block] (bin-major) for the scan. LDS atomics only.

__global__ __launch_bounds__(256) void prep_kernel(const float* __restrict__ X,
                                                   const float* __restrict__ W0,
                                                   const float* __restrict__ a_src,
                                                   const float* __restrict__ a_dst,
                                                   __half* __restrict__ H2,
                                                   float* __restrict__ als,
                                                   float* __restrict__ ald,
                                                   const int* __restrict__ ei,
                                                   int* __restrict__ hist,
                                                   const float* __restrict__ W1,
                                                   const float* __restrict__ W2,
                                                   __half* __restrict__ Wt1,
                                                   __half* __restrict__ Wt2) {
    int t = threadIdx.x;
    int b = blockIdx.x;
    if (b >= PROJ0_BLOCKS && b < PROJ0_BLOCKS + NB) {
        __shared__ int hb[NBIN];
        int blk = b - PROJ0_BLOCKS;
        for (int i = t; i < NBIN; i += 256) hb[i] = 0;
        __syncthreads();
        int base = blk * 2048 + t;
#pragma unroll
        for (int k = 0; k < 8; k++) {
            int idx = base + k * 256;
            if (idx < EP) {
                int d = (idx < EE) ? ei[EE + idx] : (idx - EE);
                atomicAdd(&hb[d >> 8], 1);   // LDS atomic, no return needed
            }
        }
        __syncthreads();
        for (int i = t; i < NBIN; i += 256) hist[i * NB + blk] = hb[i];
        return;
    }
    if (b >= PROJ0_BLOCKS + NB) {
        // 2 blocks: transpose+cast W1/W2 (128x128) into Wt[c][k] fp16.
        int l = b - (PROJ0_BLOCKS + NB);
        const float* Wsrc = (l == 0) ? W1 : W2;
        __half* Wd = (l == 0) ? Wt1 : Wt2;
#pragma unroll 8
        for (int r = 0; r < 64; r++) {
            int idx = r * 256 + t;
            int k = idx >> 7, c = idx & 127;
            Wd[c * 128 + k] = __float2half(Wsrc[idx]);
        }
        return;
    }
    // ---- proj0: 64 nodes x 128 chans, 4x8 micro-tile, K=32 single tile ----
    __shared__ float xs[32][68];
    __shared__ float ws[32][128];
    int node0 = b * 64;
    int nt = t & 15;
    int ct = t >> 4;
    float acc[4][8];
#pragma unroll
    for (int i = 0; i < 4; i++)
#pragma unroll
        for (int j = 0; j < 8; j++) acc[i][j] = 0.f;
#pragma unroll
    for (int r = 0; r < 8; r++) {
        int idx = r * 256 + t;
        int n = idx >> 5, k = idx & 31;
        xs[k][n] = X[(node0 + n) * FIN0 + k];
    }
#pragma unroll
    for (int r = 0; r < 16; r++) {
        int idx = r * 256 + t;
        int k = idx >> 7, c = idx & 127;
        ws[k][c] = W0[k * 128 + c];
    }
    __syncthreads();
#pragma unroll
    for (int k = 0; k < 32; k++) {
        const float4 xv = *(const float4*)(&xs[k][4 * nt]);
        const float4 wa = *(const float4*)(&ws[k][8 * ct]);
        const float4 wb = *(const float4*)(&ws[k][8 * ct + 4]);
        float xr[4] = {xv.x, xv.y, xv.z, xv.w};
        float wr[8] = {wa.x, wa.y, wa.z, wa.w, wb.x, wb.y, wb.z, wb.w};
#pragma unroll
        for (int i = 0; i < 4; i++)
#pragma unroll
            for (int j = 0; j < 8; j++) acc[i][j] = fmaf(xr[i], wr[j], acc[i][j]);
    }
#pragma unroll
    for (int i = 0; i < 4; i++) {
        int n = node0 + 4 * nt + i;
        __half2 p0 = __floats2half2_rn(acc[i][0], acc[i][1]);
        __half2 p1 = __floats2half2_rn(acc[i][2], acc[i][3]);
        __half2 p2 = __floats2half2_rn(acc[i][4], acc[i][5]);
        __half2 p3 = __floats2half2_rn(acc[i][6], acc[i][7]);
        uint4 pk;
        pk.x = *(unsigned*)&p0; pk.y = *(unsigned*)&p1;
        pk.z = *(unsigned*)&p2; pk.w = *(unsigned*)&p3;
        *(uint4*)(&H2[(size_t)n * HC + 8 * ct]) = pk;
    }
    float sa[4] = {0.f, 0.f, 0.f, 0.f}, da[4] = {0.f, 0.f, 0.f, 0.f};
#pragma unroll
    for (int j = 0; j < 8; j++) {
        float av = a_src[ct * 8 + j];
        float dv = a_dst[ct * 8 + j];
#pragma unroll
        for (int i = 0; i < 4; i++) {
            sa[i] = fmaf(acc[i][j], av, sa[i]);
            da[i] = fmaf(acc[i][j], dv, da[i]);
        }
    }
#pragma unroll
    for (int i = 0; i < 4; i++) {
        sa[i] += __shfl_xor(sa[i], 16);
        da[i] += __shfl_xor(da[i], 16);
    }
    if ((ct & 1) == 0) {
        int head = ct >> 1;
#pragma unroll
        for (int i = 0; i < 4; i++) {
            int n = node0 + 4 * nt + i;
            als[n * 8 + head] = sa[i];
            ald[n * 8 + head] = da[i];
        }
    }
}

// ---------------- scan of hist[bin][block] (52281 elements, exclusive) ----------------

__global__ __launch_bounds__(256) void scan_partial2(const int* __restrict__ hist,
                                                     int* __restrict__ part) {
    int b = blockIdx.x, t = threadIdx.x;
    int i = b * 256 + t;
    int v = (i < HSIZE) ? hist[i] : 0;
#pragma unroll
    for (int d = 1; d < 64; d <<= 1) v += __shfl_xor(v, d);
    __shared__ int ws[4];
    if ((t & 63) == 0) ws[t >> 6] = v;
    __syncthreads();
    if (t == 0) part[b] = ws[0] + ws[1] + ws[2] + ws[3];
}

__global__ __launch_bounds__(256) void scan_final2(const int* __restrict__ hist,
                                                   const int* __restrict__ part,
                                                   int* __restrict__ base) {
    int b = blockIdx.x, t = threadIdx.x;
    __shared__ int sbase;
    if (t < 64) {
        int s = 0;
        for (int l = t; l < b; l += 64) s += part[l];
#pragma unroll
        for (int d = 1; d < 64; d <<= 1) s += __shfl_xor(s, d);
        if (t == 0) sbase = s;
    }
    int i = b * 256 + t;
    int v = (i < HSIZE) ? hist[i] : 0;
    __shared__ int tmp[256];
    tmp[t] = v;
    __syncthreads();
    for (int st = 1; st < 256; st <<= 1) {
        int add = (t >= st) ? tmp[t - st] : 0;
        __syncthreads();
        tmp[t] += add;
        __syncthreads();
    }
    int excl = tmp[t] - v + sbase;
    if (i < HSIZE) base[i] = excl;
}

// ---------------- C1: deterministic bucket scatter (packed dst<<16|src) ----------------

__global__ __launch_bounds__(256) void radix_c1(const int* __restrict__ ei,
                                                const int* __restrict__ base,
                                                unsigned* __restrict__ tmp) {
    __shared__ int lbase[NBIN];
    __shared__ int lcnt[NBIN];
    int t = threadIdx.x, blk = blockIdx.x;
    for (int i = t; i < NBIN; i += 256) { lbase[i] = base[i * NB + blk]; lcnt[i] = 0; }
    __syncthreads();
    int start = blk * 2048 + t;
#pragma unroll
    for (int k = 0; k < 8; k++) {
        int idx = start + k * 256;
        if (idx < EP) {
            int s, d;
            if (idx < EE) { s = ei[idx]; d = ei[EE + idx]; } else { s = idx - EE; d = s; }
            int bin = d >> 8;
            int r = atomicAdd(&lcnt[bin], 1);          // LDS atomic (returning)
            tmp[lbase[bin] + r] = ((unsigned)d << 16) | (unsigned)s;
        }
    }
}

// ---------------- P2: per-bucket low-byte CSR (one block per high-byte bucket) ----------------
// Bucket k holds tmp[binbase[k], binbase[k+1]) — ~4350 edges, 17KB, L2-hot.
// LDS count -> ladder scan -> offs[d] direct (empty dsts get correct boundaries)
// -> LDS-cursor scatter of src into esrc. No stability needed (MSD).

__global__ __launch_bounds__(256) void radix_p2(const unsigned* __restrict__ tmp,
                                                const int* __restrict__ base,
                                                int* __restrict__ esrc,
                                                int* __restrict__ offs) {
    __shared__ int cnt[256];
    __shared__ int sc[256];
    int t = threadIdx.x, k = blockIdx.x;
    int bb = base[k * NB];
    int be = (k == NBIN - 1) ? EP : base[(k + 1) * NB];
    cnt[t] = 0;
    __syncthreads();
    for (int e = bb + t; e < be; e += 256) {
        unsigned v = tmp[e];
        atomicAdd(&cnt[(v >> 16) & 255], 1);
    }
    __syncthreads();
    int myc = cnt[t];
    sc[t] = myc;
    __syncthreads();
    for (int st = 1; st < 256; st <<= 1) {
        int add = (t >= st) ? sc[t - st] : 0;
        __syncthreads();
        sc[t] += add;
        __syncthreads();
    }
    int ex = sc[t] - myc;   // exclusive prefix within bucket
    int d = k * 256 + t;
    if (d < NN) offs[d] = bb + ex;
    if (k == NBIN - 1 && t == 0) offs[NN] = EP;
    __syncthreads();
    cnt[t] = ex;            // reuse as cursor
    __syncthreads();
    for (int e = bb + t; e < be; e += 256) {
        unsigned v = tmp[e];
        int d0 = (v >> 16) & 255;
        int r = atomicAdd(&cnt[d0], 1);
        esrc[bb + r] = (int)(v & 0xFFFFu);
    }
}

// ---------------- MFMA projection for layers 1-2 (FIN = HC = 128) ----------------
// R9-R11: mfma_f32_16x16x32_f16, 32 MFMA/wave, K=128 in 4 k-steps; staging walks
// fixed in R10 (Ws) and R11 (As + H2 writeback). Verified R11 @ absmax 1.2e-4.
// Layouts (m89-verified family): A row=l&15,k=(l>>4)*8+i; B k=(l>>4)*8+i,col=l&15;
// C/D col=l&15,row=(l>>4)*4+j.
// LDS: As 64xPADH + Ws 128xPADH halves = 52.2 KB -> 3 blocks/CU; grid 625.

__global__ __launch_bounds__(256) void proj_mfma(const __half* __restrict__ Bin,
                                                 const __half* __restrict__ Wt,
                                                 const float* __restrict__ a_src,
                                                 const float* __restrict__ a_dst,
                                                 __half* __restrict__ H2,
                                                 float* __restrict__ als,
                                                 float* __restrict__ ald) {
    __shared__ __half As[64 * PADH];
    __shared__ __half Ws[128 * PADH];
    int t = threadIdx.x;
    int node0 = blockIdx.x * 64;
    {   // stage A-tile: 64 nodes x 128 k fp16 = 1024 uint4, 4 per thread
        int n = t >> 2, kk = (t & 3) * 32;
        const uint4* src = (const uint4*)(&Bin[(size_t)(node0 + n) * 128 + kk]);
        uint4 v0 = src[0];
        uint4 v1 = src[1];
        uint4 v2 = src[2];
        uint4 v3 = src[3];
        uint4* dst = (uint4*)(&As[n * PADH + kk]);   // PADH*2B = 272 = 17x16B
        dst[0] = v0; dst[1] = v1; dst[2] = v2; dst[3] = v3;
    }
#pragma unroll
    for (int r = 0; r < 8; r++) {  // stage Wt: 128 rows x 16 chunks of 8 halves
        int idx = r * 256 + t;
        int c = idx >> 4;
        int kk = (idx & 15) * 8;
        uint4 v = *(const uint4*)(&Wt[c * 128 + kk]);
        *(uint4*)(&Ws[c * PADH + kk]) = v;
    }
    __syncthreads();
    int w = t >> 6, l = t & 63;
    int lr = l & 15, lg = l >> 4;
    f32x4 acc[8];
    f32x4 z4 = {0.f, 0.f, 0.f, 0.f};
#pragma unroll
    for (int n = 0; n < 8; n++) acc[n] = z4;
    const __half* arow = &As[(16 * w + lr) * PADH + lg * 8];
#pragma unroll
    for (int ks = 0; ks < 4; ks++) {
        f16x8 af = *(const f16x8*)(arow + 32 * ks);
#pragma unroll
        for (int n = 0; n < 8; n++) {
            f16x8 bf = *(const f16x8*)(&Ws[(16 * n + lr) * PADH + lg * 8 + 32 * ks]);
            acc[n] = __builtin_amdgcn_mfma_f32_16x16x32_f16(af, bf, acc[n], 0, 0, 0);
        }
    }
    // write C tile (fp16) into own 16 rows of As; wave-private rows, DS in-order
    // per wave and the writes depend on the MFMA results.
#pragma unroll
    for (int n = 0; n < 8; n++)
#pragma unroll
        for (int j = 0; j < 4; j++)
            As[(16 * w + lg * 4 + j) * PADH + 16 * n + lr] = __float2half(acc[n][j]);
    __syncthreads();
    {   // coalesced H2 write-back: 4 uint4 per thread, contiguous
        int n = t >> 2, kk = (t & 3) * 32;
        const uint4* src = (const uint4*)(&As[n * PADH + kk]);
        uint4 v0 = src[0];
        uint4 v1 = src[1];
        uint4 v2 = src[2];
        uint4 v3 = src[3];
        uint4* dst = (uint4*)(&H2[(size_t)(node0 + n) * 128 + kk]);
        dst[0] = v0; dst[1] = v1; dst[2] = v2; dst[3] = v3;
    }
    {   // attention logits from the fp16 tile (same mapping as proj0 epilogue)
        int nt = t & 15, ct = t >> 4;
        float av[8], dv[8];
#pragma unroll
        for (int j = 0; j < 8; j++) { av[j] = a_src[ct * 8 + j]; dv[j] = a_dst[ct * 8 + j]; }
        float sa[4], da[4];
#pragma unroll
        for (int i = 0; i < 4; i++) {
            uint4 hv = *(const uint4*)(&As[(4 * nt + i) * PADH + 8 * ct]);
            __half2 h0 = *(__half2*)&hv.x;
            __half2 h1 = *(__half2*)&hv.y;
            __half2 h2 = *(__half2*)&hv.z;
            __half2 h3 = *(__half2*)&hv.w;
            float2 f0 = __half22float2(h0);
            float2 f1 = __half22float2(h1);
            float2 f2 = __half22float2(h2);
            float2 f3 = __half22float2(h3);
            sa[i] = f0.x * av[0] + f0.y * av[1] + f1.x * av[2] + f1.y * av[3] +
                    f2.x * av[4] + f2.y * av[5] + f3.x * av[6] + f3.y * av[7];
            da[i] = f0.x * dv[0] + f0.y * dv[1] + f1.x * dv[2] + f1.y * dv[3] +
                    f2.x * dv[4] + f2.y * dv[5] + f3.x * dv[6] + f3.y * dv[7];
        }
#pragma unroll
        for (int i = 0; i < 4; i++) {
            sa[i] += __shfl_xor(sa[i], 16);
            da[i] += __shfl_xor(da[i], 16);
        }
        if ((ct & 1) == 0) {
            int head = ct >> 1;
#pragma unroll
            for (int i = 0; i < 4; i++) {
                int n = node0 + 4 * nt + i;
                als[n * 8 + head] = sa[i];
                ald[n * 8 + head] = da[i];
            }
        }
    }
}

// ---------------- fused softmax + aggregation per dst node ----------------
// R11 form (verified). At the random-256B-gather ceiling (~3.6 TB/s; confirmed by
// two failed locality splits, R8 and R12). HALF_OUT: layers 0/1 emit fp16 B2,
// layer 2 fp32 B for the MLP.

template <bool HALF_OUT>
__global__ __launch_bounds__(256) void agg_kernel(const __half* __restrict__ H2,
                                                  const float* __restrict__ als,
                                                  const float* __restrict__ ald,
                                                  const int* __restrict__ offs,
                                                  const int* __restrict__ esrc,
                                                  const float* __restrict__ bias,
                                                  float* __restrict__ OUT,
                                                  __half* __restrict__ OUT2) {
    int t = threadIdx.x;
    int n = blockIdx.x * 4 + (t >> 6);
    int t6 = t & 63;
    int c8 = t6 & 15;          // channel group: chans [8*c8, 8*c8+8)
    int slot = (t6 >> 4) & 3;  // 4 edge slots per wave
    int hd = c8 >> 1;
    int beg = offs[n], end = offs[n + 1];
    float ad = ald[n * 8 + hd];
    float acc[8] = {0.f, 0.f, 0.f, 0.f, 0.f, 0.f, 0.f, 0.f};
    float denom = 0.f;
    const float4* H4 = (const float4*)H2;   // 8 halves per float4

    int p = beg + slot;
    int s_cur = 0; float al_cur = 0.f;
    if (p < end) {
        s_cur = esrc[p];
        al_cur = als[s_cur * 8 + hd];
    }
#pragma unroll 2
    while (p < end) {
        int pn = p + 4;
        int s_nxt = 0;
        if (pn < end) s_nxt = esrc[pn];
        float x = al_cur + ad;
        x = (x > 0.f) ? x : 0.2f * x;
        float w = __expf(x);
        float4 r = H4[(size_t)s_cur * 16 + c8];
        float al_nxt = 0.f;
        if (pn < end) al_nxt = als[s_nxt * 8 + hd];
        __half2 h0 = *(__half2*)&r.x;
        __half2 h1 = *(__half2*)&r.y;
        __half2 h2 = *(__half2*)&r.z;
        __half2 h3 = *(__half2*)&r.w;
        float2 f0 = __half22float2(h0);
        float2 f1 = __half22float2(h1);
        float2 f2 = __half22float2(h2);
        float2 f3 = __half22float2(h3);
        acc[0] = fmaf(w, f0.x, acc[0]); acc[1] = fmaf(w, f0.y, acc[1]);
        acc[2] = fmaf(w, f1.x, acc[2]); acc[3] = fmaf(w, f1.y, acc[3]);
        acc[4] = fmaf(w, f2.x, acc[4]); acc[5] = fmaf(w, f2.y, acc[5]);
        acc[6] = fmaf(w, f3.x, acc[6]); acc[7] = fmaf(w, f3.y, acc[7]);
        denom += w;
        s_cur = s_nxt; al_cur = al_nxt;
        p = pn;
    }
#pragma unroll
    for (int j = 0; j < 8; j++) {
        acc[j] += __shfl_xor(acc[j], 16);
        acc[j] += __shfl_xor(acc[j], 32);
    }
    denom += __shfl_xor(denom, 16);
    denom += __shfl_xor(denom, 32);
    if (slot == 0 && t6 < 16) {
        float inv = 1.0f / denom;
        const float4 ba = ((const float4*)bias)[2 * c8];
        const float4 bb = ((const float4*)bias)[2 * c8 + 1];
        float o0 = fmaxf(fmaf(acc[0], inv, ba.x), 0.f);
        float o1 = fmaxf(fmaf(acc[1], inv, ba.y), 0.f);
        float o2 = fmaxf(fmaf(acc[2], inv, ba.z), 0.f);
        float o3 = fmaxf(fmaf(acc[3], inv, ba.w), 0.f);
        float o4 = fmaxf(fmaf(acc[4], inv, bb.x), 0.f);
        float o5 = fmaxf(fmaf(acc[5], inv, bb.y), 0.f);
        float o6 = fmaxf(fmaf(acc[6], inv, bb.z), 0.f);
        float o7 = fmaxf(fmaf(acc[7], inv, bb.w), 0.f);
        if (HALF_OUT) {
            __half2 q0 = __floats2half2_rn(o0, o1);
            __half2 q1 = __floats2half2_rn(o2, o3);
            __half2 q2 = __floats2half2_rn(o4, o5);
            __half2 q3 = __floats2half2_rn(o6, o7);
            uint4 pk;
            pk.x = *(unsigned*)&q0; pk.y = *(unsigned*)&q1;
            pk.z = *(unsigned*)&q2; pk.w = *(unsigned*)&q3;
            ((uint4*)OUT2)[(size_t)n * 16 + c8] = pk;
        } else {
            float4 v0, v1;
            v0.x = o0; v0.y = o1; v0.z = o2; v0.w = o3;
            v1.x = o4; v1.y = o5; v1.z = o6; v1.w = o7;
            ((float4*)OUT)[(size_t)n * 32 + 2 * c8]     = v0;
            ((float4*)OUT)[(size_t)n * 32 + 2 * c8 + 1] = v1;
        }
    }
}

// ---------------- fused mean-pool + MLP + head (2 graphs/block, 500 blocks) ----------------

__global__ __launch_bounds__(256) void mlp_fused(const float* __restrict__ B,
                                                 const int* __restrict__ batch,
                                                 const float* __restrict__ fW0,
                                                 const float* __restrict__ fb0,
                                                 const float* __restrict__ fW1,
                                                 const float* __restrict__ fb1,
                                                 const float* __restrict__ oW,
                                                 const float* __restrict__ ob,
                                                 float* __restrict__ out) {
    __shared__ int lo[3];
    __shared__ float rows[2][128];
    __shared__ float g1s[2][256];
    __shared__ float g2s[2][256];
    int t = threadIdx.x;
    int g0 = blockIdx.x * 2;
    if (t < 3) {
        int target = g0 + t;
        int a = 0, b = NN;
        while (a < b) { int mid = (a + b) >> 1; if (batch[mid] < target) a = mid + 1; else b = mid; }
        lo[t] = a;
    }
    __syncthreads();
    {
        int j = t >> 7, c = t & 127;
        int s0 = lo[j], s1 = lo[j + 1];
        float s = 0.f;
        float p0 = 0.f, p1 = 0.f, p2 = 0.f, p3 = 0.f;
        int n = s0;
        for (; n + 3 < s1; n += 4) {
            p0 += B[(size_t)n * 128 + c];
            p1 += B[(size_t)(n + 1) * 128 + c];
            p2 += B[(size_t)(n + 2) * 128 + c];
            p3 += B[(size_t)(n + 3) * 128 + c];
        }
        for (; n < s1; n++) s += B[(size_t)n * 128 + c];
        s += (p0 + p1) + (p2 + p3);
        rows[j][c] = s / fmaxf((float)(s1 - s0), 1.0f);
    }
    __syncthreads();
    float a0 = 0.f, a1 = 0.f;
#pragma unroll 8
    for (int k = 0; k < 128; k++) {
        float w = fW0[k * 256 + t];
        a0 = fmaf(rows[0][k], w, a0);
        a1 = fmaf(rows[1][k], w, a1);
    }
    float b0v = fb0[t];
    g1s[0][t] = fmaxf(a0 + b0v, 0.f);
    g1s[1][t] = fmaxf(a1 + b0v, 0.f);
    __syncthreads();
    a0 = 0.f; a1 = 0.f;
#pragma unroll 8
    for (int k = 0; k < 256; k++) {
        float w = fW1[k * 256 + t];
        a0 = fmaf(g1s[0][k], w, a0);
        a1 = fmaf(g1s[1][k], w, a1);
    }
    float b1v = fb1[t];
    g2s[0][t] = fmaxf(a0 + b1v, 0.f);
    g2s[1][t] = fmaxf(a1 + b1v, 0.f);
    __syncthreads();
    if (t < 64) {
        int jj = t >> 5, l = t & 31;
        float p0 = 0.f, p1 = 0.f;
#pragma unroll
        for (int k = l; k < 256; k += 32) {
            float v = g2s[jj][k];
            p0 = fmaf(v, oW[k * 2 + 0], p0);
            p1 = fmaf(v, oW[k * 2 + 1], p1);
        }
#pragma unroll
        for (int d = 1; d < 32; d <<= 1) {
            p0 += __shfl_xor(p0, d);
            p1 += __shfl_xor(p1, d);
        }
        if (l == 0) {
            out[(g0 + jj) * 2 + 0] = p0 + ob[0];
            out[(g0 + jj) * 2 + 1] = p1 + ob[1];
        }
    }
}

// ---------------- launch ----------------

extern "C" void kernel_launch(void* const* d_in, const int* in_sizes, int n_in,
                              void* d_out, int out_size, void* d_ws, size_t ws_size,
                              hipStream_t stream) {
    const float* x    = (const float*)d_in[0];
    const int* ei     = (const int*)d_in[1];
    const int* batch  = (const int*)d_in[2];
    const float* W[3]   = {(const float*)d_in[3], (const float*)d_in[7],  (const float*)d_in[11]};
    const float* bs[3]  = {(const float*)d_in[4], (const float*)d_in[8],  (const float*)d_in[12]};
    const float* asr[3] = {(const float*)d_in[5], (const float*)d_in[9],  (const float*)d_in[13]};
    const float* adt[3] = {(const float*)d_in[6], (const float*)d_in[10], (const float*)d_in[14]};
    const float* fW0 = (const float*)d_in[15];
    const float* fb0 = (const float*)d_in[16];
    const float* fW1 = (const float*)d_in[17];
    const float* fb1 = (const float*)d_in[18];
    const float* oW  = (const float*)d_in[19];
    const float* ob  = (const float*)d_in[20];
    float* out = (float*)d_out;

    char* base_ws = (char*)d_ws;
    size_t off = 0;
    auto alloc = [&](size_t bytes) -> void* {
        void* p = base_ws + off;
        off += (bytes + 255) & ~(size_t)255;
        return p;
    };
    int* hist     = (int*)alloc((size_t)HSIZE * 4);
    int* sbase    = (int*)alloc((size_t)HSIZE * 4);
    int* part     = (int*)alloc((size_t)SCAN2_BLOCKS * 4);
    unsigned* tmp = (unsigned*)alloc((size_t)EP * 4);
    int* offs     = (int*)alloc((size_t)(NN + 1) * 4);
    int* esrc     = (int*)alloc((size_t)EP * 4);
    __half* H2  = (__half*)alloc((size_t)NN * HC * 2);
    float* B    = (float*)alloc((size_t)NN * HC * 4);
    __half* B2  = (__half*)alloc((size_t)NN * HC * 2);
    float* als  = (float*)alloc((size_t)NN * 8 * 4);
    float* ald  = (float*)alloc((size_t)NN * 8 * 4);
    __half* Wt1 = (__half*)alloc((size_t)HC * HC * 2);
    __half* Wt2 = (__half*)alloc((size_t)HC * HC * 2);

    prep_kernel<<<PROJ0_BLOCKS + NB + 2, 256, 0, stream>>>(
        x, W[0], asr[0], adt[0], H2, als, ald, ei, hist, W[1], W[2], Wt1, Wt2);
    scan_partial2<<<SCAN2_BLOCKS, 256, 0, stream>>>(hist, part);
    scan_final2<<<SCAN2_BLOCKS, 256, 0, stream>>>(hist, part, sbase);
    radix_c1<<<NB, 256, 0, stream>>>(ei, sbase, tmp);
    radix_p2<<<NBIN, 256, 0, stream>>>(tmp, sbase, esrc, offs);

    agg_kernel<true><<<NN / 4, 256, 0, stream>>>(H2, als, ald, offs, esrc, bs[0], nullptr, B2);
    proj_mfma<<<PROJ0_BLOCKS, 256, 0, stream>>>(B2, Wt1, asr[1], adt[1], H2, als, ald);
    agg_kernel<true><<<NN / 4, 256, 0, stream>>>(H2, als, ald, offs, esrc, bs[1], nullptr, B2);
    proj_mfma<<<PROJ0_BLOCKS, 256, 0, stream>>>(B2, Wt2, asr[2], adt[2], H2, als, ald);
    agg_kernel<false><<<NN / 4, 256, 0, stream>>>(H2, als, ald, offs, esrc, bs[2], B, nullptr);

    mlp_fused<<<GG / 2, 256, 0, stream>>>(B, batch, fW0, fb0, fW1, fb1, oW, ob, out);
}